// Round 8
// baseline (209.553 us; speedup 1.0000x reference)
//
#include <hip/hip_runtime.h>
#include <stdint.h>

// ListwiseLoss: B=524288 rows, H=32.
//   kl_row = sum_valid e_i*(s_i - g_i) / se,  e = exp(s),
//   g_i = s of the (rank_i)-th valid element in index order
// (max-sub and log(se) cancel between the KL sums; eps dropped — validated
//  rounds 1-14, absmax 0.0).
//
// Round-15: same wave-cooperative packed-sort structure as R14 (validated),
// with the two measured inefficiencies fixed:
//  * R14 VALU-busy stayed ~45us: cex scalarized (4x cmp+cndmask) and the
//    per-stage tm select re-materialized v_cmp each stage. Now: compare-
//    exchange = v_pk_min_u16 + v_pk_max_u16 (__builtin_elementwise_min/max
//    on ushort2) + v_bfi_b32 with 15 PRECOMPUTED direction-mask VGPRs
//    (lane-invariant -> hoisted once per wave). 3 VALU/stage, zero cmp.
//  * j=8 exchange via DPP row_ror:8 (rotate-8 within 16-rows == xor-8):
//    sort DS ops 6 -> 4 per group (j=4 x3, j=16 x1 remain shfl).
//  * ILP=2: TWO groups (8 rows) per loop iteration — two independent sort
//    chains + reduction ladders interleave, covering shfl/DPP latency that
//    single-chain waves exposed (R13/R14 wall-VALU gap ~47us).
// Layout per group G: lane 32h+e5 holds elem e5 of rows {4G+h} (lo16) and
// {4G+2+h} (hi16). Loads: elem = 128G + {0,64} + lane; pair of groups
// covers 256 contiguous elements. 1-deep prefetch, no launch_bounds cap.
// pred-order g via ds_permute push (ballot+mbcnt slots), rank-side score
// via ds_bpermute pull on sorted idx, DPP-ladder reductions (all validated).

#define H 32
#define BLK 256
#define WPB 4

typedef unsigned short us2 __attribute__((ext_vector_type(2)));
union UP { uint32_t u; us2 v; };

template<int CTRL>
__device__ __forceinline__ uint32_t dppmov_u(uint32_t x) {
    return (uint32_t)__builtin_amdgcn_update_dpp(0, (int)x, CTRL, 0xF, 0xF, true);
}
template<int CTRL>
__device__ __forceinline__ float dppmov_f(float x) {
    return __int_as_float(
        __builtin_amdgcn_update_dpp(0, __float_as_int(x), CTRL, 0xF, 0xF, true));
}

// sum over each 32-lane half; lanes 31 and 63 hold their half's total
__device__ __forceinline__ float half_sum32(float v) {
    v += dppmov_f<0x111>(v);   // row_shr:1
    v += dppmov_f<0x112>(v);   // row_shr:2
    v += dppmov_f<0x114>(v);   // row_shr:4
    v += dppmov_f<0x118>(v);   // row_shr:8
    v += dppmov_f<0x142>(v);   // row_bcast:15
    return v;
}

// One group = 4 rows: {4G+h} in lo16 ("A"), {4G+2+h} in hi16 ("B").
__device__ __forceinline__ void proc_group(
    const uint32_t (&DM)[15],
    int rvA, int rvB, float svA, float svB, uint32_t mmA, uint32_t mmB,
    int rowA, int nrows, int e5, int h,
    float& kl_acc, float& cnt_acc)
{
    const int rowB = rowA + 2;
    const bool vA = (rowA < nrows) && (mmA != 0u) && (rvA > 0);
    const bool vB = (rowB < nrows) && (mmB != 0u) && (rvB > 0);

    // bf16-rounded scores (consistent with rounds 1-14)
    const float sA = __uint_as_float(((__float_as_uint(svA) + 0x8000u) >> 16) << 16);
    const float sB = __uint_as_float(((__float_as_uint(svB) + 0x8000u) >> 16) << 16);

    // u16 keys: valid -> (r<<5)|idx (<=0x43F), invalid -> 0x8000|idx
    const uint32_t e5u = (uint32_t)e5;
    const uint32_t kA = vA ? (((uint32_t)rvA << 5) | e5u) : (0x8000u | e5u);
    const uint32_t kB = vB ? (((uint32_t)rvB << 5) | e5u) : (0x8000u | e5u);
    uint32_t W = kA | (kB << 16);

    // ---- idx-order compacted slots via ballot+mbcnt (bijective push) ----
    const unsigned long long bmA = __ballot(vA);
    const unsigned long long bmB = __ballot(vB);
    const uint32_t lo_pcA = __builtin_popcount((uint32_t)bmA);
    const uint32_t lo_pcB = __builtin_popcount((uint32_t)bmB);
    const uint32_t belowA = __builtin_amdgcn_mbcnt_hi(
        (uint32_t)(bmA >> 32), __builtin_amdgcn_mbcnt_lo((uint32_t)bmA, 0u));
    const uint32_t belowB = __builtin_amdgcn_mbcnt_hi(
        (uint32_t)(bmB >> 32), __builtin_amdgcn_mbcnt_lo((uint32_t)bmB, 0u));
    const int qA = (int)belowA - (h ? (int)lo_pcA : 0);
    const int qB = (int)belowB - (h ? (int)lo_pcB : 0);
    const int nvA = h ? __builtin_popcount((uint32_t)(bmA >> 32)) : (int)lo_pcA;
    const int nvB = h ? __builtin_popcount((uint32_t)(bmB >> 32)) : (int)lo_pcB;
    const int slotA = (vA ? qA : nvA + (e5 - qA)) + (h << 5);
    const int slotB = (vB ? qB : nvB + (e5 - qB)) + (h << 5);
    const float gA = __int_as_float(
        __builtin_amdgcn_ds_permute(slotA << 2, __float_as_int(sA)));
    const float gB = __int_as_float(
        __builtin_amdgcn_ds_permute(slotB << 2, __float_as_int(sB)));

    // ---- packed bitonic sort across each 32-lane half ----
    // exchange: j=1,2 quad_perm DPP; j=8 row_ror:8 DPP (xor-8 in 16-rows);
    // j=4,16 shfl. CE = pk_min + pk_max + bfi with hoisted dir masks.
    int sidx = 0;
    #pragma unroll
    for (int k = 2; k <= 32; k <<= 1) {
        #pragma unroll
        for (int j = k >> 1; j > 0; j >>= 1) {
            uint32_t Wo;
            if (j == 1)      Wo = dppmov_u<0xB1>(W);   // quad_perm[1,0,3,2]
            else if (j == 2) Wo = dppmov_u<0x4E>(W);   // quad_perm[2,3,0,1]
            else if (j == 8) Wo = dppmov_u<0x128>(W);  // row_ror:8
            else             Wo = (uint32_t)__shfl_xor((int)W, j);
            UP a, b, mn, mx;
            a.u = W; b.u = Wo;
            mn.v = __builtin_elementwise_min(a.v, b.v);  // v_pk_min_u16
            mx.v = __builtin_elementwise_max(a.v, b.v);  // v_pk_max_u16
            const uint32_t D = DM[sidx]; ++sidx;
            W = (mn.u & ~D) | (mx.u & D);                // v_bfi_b32
        }
    }

    // ---- rank-position p = e5: pull score via sorted idx ----
    const uint32_t WA = W & 0xFFFFu, WB = W >> 16;
    const bool vA2 = (WA & 0x8000u) == 0u;     // p < nvA
    const bool vB2 = (WB & 0x8000u) == 0u;
    const int iA = (int)(WA & 31u), iB = (int)(WB & 31u);
    const float srA = __int_as_float(__builtin_amdgcn_ds_bpermute(
        (((h << 5) | iA) << 2), __float_as_int(sA)));
    const float srB = __int_as_float(__builtin_amdgcn_ds_bpermute(
        (((h << 5) | iB) << 2), __float_as_int(sB)));

    float eA = __expf(srA); eA = vA2 ? eA : 0.0f;
    float eB = __expf(srB); eB = vB2 ? eB : 0.0f;
    const float tA = eA * (srA - gA);
    const float tB = eB * (srB - gB);

    const float seA = half_sum32(eA);
    const float seB = half_sum32(eB);
    const float nmA = half_sum32(tA);
    const float nmB = half_sum32(tB);

    const float cA = (nvA > 1) ? __fdividef(nmA, seA) : 0.0f;
    const float cB = (nvB > 1) ? __fdividef(nmB, seB) : 0.0f;
    if (e5 == 31) {
        kl_acc  += cA + cB;
        cnt_acc += (nvA > 1 ? 1.0f : 0.0f) + (nvB > 1 ? 1.0f : 0.0f);
    }
}

__device__ __forceinline__ void load_pair(
    const float* __restrict__ scores, const int* __restrict__ rankings,
    const unsigned char* __restrict__ mask_u8, bool mask_is_i32,
    size_t base, int lane, size_t total,
    int& r0, int& r1, int& r2, int& r3,
    float& s0, float& s1, float& s2, float& s3,
    uint32_t& m0, uint32_t& m1, uint32_t& m2, uint32_t& m3)
{
    if (base + 256 <= total) {          // fast path: wave-uniform, unclamped
        const size_t o = base + (size_t)lane;
        r0 = rankings[o];       r1 = rankings[o + 64];
        r2 = rankings[o + 128]; r3 = rankings[o + 192];
        s0 = scores[o];         s1 = scores[o + 64];
        s2 = scores[o + 128];   s3 = scores[o + 192];
        if (mask_is_i32) {
            const int* mp = (const int*)mask_u8;
            m0 = (uint32_t)mp[o];       m1 = (uint32_t)mp[o + 64];
            m2 = (uint32_t)mp[o + 128]; m3 = (uint32_t)mp[o + 192];
        } else {
            m0 = mask_u8[o];       m1 = mask_u8[o + 64];
            m2 = mask_u8[o + 128]; m3 = mask_u8[o + 192];
        }
    } else {                            // tail: clamp each (validity re-checked)
        const size_t mi = total - 1;
        size_t o0 = base + (size_t)lane;        if (o0 > mi) o0 = mi;
        size_t o1 = base + (size_t)lane + 64;   if (o1 > mi) o1 = mi;
        size_t o2 = base + (size_t)lane + 128;  if (o2 > mi) o2 = mi;
        size_t o3 = base + (size_t)lane + 192;  if (o3 > mi) o3 = mi;
        r0 = rankings[o0]; r1 = rankings[o1]; r2 = rankings[o2]; r3 = rankings[o3];
        s0 = scores[o0];   s1 = scores[o1];   s2 = scores[o2];   s3 = scores[o3];
        if (mask_is_i32) {
            const int* mp = (const int*)mask_u8;
            m0 = (uint32_t)mp[o0]; m1 = (uint32_t)mp[o1];
            m2 = (uint32_t)mp[o2]; m3 = (uint32_t)mp[o3];
        } else {
            m0 = mask_u8[o0]; m1 = mask_u8[o1];
            m2 = mask_u8[o2]; m3 = mask_u8[o3];
        }
    }
}

__global__ __launch_bounds__(BLK) void listwise_kernel(
    const float* __restrict__ scores,
    const int* __restrict__ rankings,
    const unsigned char* __restrict__ mask_u8,
    float* __restrict__ part_kl,
    float* __restrict__ part_cnt,
    int nrows, int ipw)
{
    __shared__ float s_kl[WPB], s_cnt[WPB];

    const int tid  = threadIdx.x;
    const int lane = tid & 63;
    const int wid  = tid >> 6;
    const int e5   = lane & 31;
    const int h    = lane >> 5;

    const long long wave_g  = (long long)blockIdx.x * WPB + wid;
    const long long tgroups = ((long long)nrows + 3) >> 2;   // 4 rows/group
    const long long gbeg = wave_g * ipw;
    const long long gend0 = gbeg + ipw;
    const long long gend = (gend0 < tgroups) ? gend0 : tgroups;

    // mask dtype detect (bool=1B vs int32=4B); wave-uniform branch
    unsigned char probe = mask_u8[lane];
    const bool mask_is_i32 =
        (__ballot(((lane & 3) != 0) && (probe != 0)) == 0ull);

    // ---- hoisted per-lane direction masks for the 15 sort stages ----
    uint32_t DM[15];
    {
        int s = 0;
        #pragma unroll
        for (int k = 2; k <= 32; k <<= 1)
            #pragma unroll
            for (int j = k >> 1; j > 0; j >>= 1)
                DM[s++] = ((((e5 & j) == 0) != ((e5 & k) == 0))
                               ? 0xFFFFFFFFu : 0u);
    }

    float kl_acc = 0.0f, cnt_acc = 0.0f;

    if (gbeg < gend) {
        const size_t total = (size_t)nrows * H;
        const long long npairs = (gend - gbeg + 1) >> 1;

        size_t base = (size_t)gbeg * 128;
        int      cr0, cr1, cr2, cr3;
        float    cs0, cs1, cs2, cs3;
        uint32_t cm0, cm1, cm2, cm3;
        load_pair(scores, rankings, mask_u8, mask_is_i32, base, lane, total,
                  cr0, cr1, cr2, cr3, cs0, cs1, cs2, cs3, cm0, cm1, cm2, cm3);

        for (long long t = 0; t < npairs; ++t) {
            const long long G = gbeg + 2 * t;

            // ---- issue next pair's loads (1-deep prefetch) ----
            const bool last = (t + 1 >= npairs);
            const size_t nbase = last ? base : (base + 256);
            int      xr0, xr1, xr2, xr3;
            float    xs0, xs1, xs2, xs3;
            uint32_t xm0, xm1, xm2, xm3;
            load_pair(scores, rankings, mask_u8, mask_is_i32, nbase, lane, total,
                      xr0, xr1, xr2, xr3, xs0, xs1, xs2, xs3,
                      xm0, xm1, xm2, xm3);

            // ---- two independent groups: sort chains interleave (ILP=2) ----
            proc_group(DM, cr0, cr1, cs0, cs1, cm0, cm1,
                       (int)(4 * G) + h, nrows, e5, h, kl_acc, cnt_acc);
            const int rowA1 = (G + 1 < gend) ? (int)(4 * (G + 1)) + h : nrows;
            proc_group(DM, cr2, cr3, cs2, cs3, cm2, cm3,
                       rowA1, nrows, e5, h, kl_acc, cnt_acc);

            cr0 = xr0; cr1 = xr1; cr2 = xr2; cr3 = xr3;
            cs0 = xs0; cs1 = xs1; cs2 = xs2; cs3 = xs3;
            cm0 = xm0; cm1 = xm1; cm2 = xm2; cm3 = xm3;
            base = nbase;
        }
    }

    // ---- wave reduction (lanes 31/63 carry), then block partial ----
    #pragma unroll
    for (int m = 32; m >= 1; m >>= 1) {
        kl_acc  += __shfl_xor(kl_acc, m);
        cnt_acc += __shfl_xor(cnt_acc, m);
    }
    if (lane == 0) { s_kl[wid] = kl_acc; s_cnt[wid] = cnt_acc; }
    __syncthreads();
    if (tid == 0) {
        part_kl[blockIdx.x]  = s_kl[0] + s_kl[1] + s_kl[2] + s_kl[3];
        part_cnt[blockIdx.x] = s_cnt[0] + s_cnt[1] + s_cnt[2] + s_cnt[3];
    }
}

__global__ __launch_bounds__(256) void finalize_kernel(
    const float* __restrict__ part_kl,
    const float* __restrict__ part_cnt,
    float* __restrict__ out, int nblk)
{
    float k = 0.0f, c = 0.0f;
    for (int i = threadIdx.x; i < nblk; i += 256) {
        k += part_kl[i];
        c += part_cnt[i];
    }
    #pragma unroll
    for (int m = 32; m >= 1; m >>= 1) {
        k += __shfl_xor(k, m);
        c += __shfl_xor(c, m);
    }
    __shared__ float sk[4], sc[4];
    const int wid = threadIdx.x >> 6;
    if ((threadIdx.x & 63) == 0) { sk[wid] = k; sc[wid] = c; }
    __syncthreads();
    if (threadIdx.x == 0) {
        float K = sk[0] + sk[1] + sk[2] + sk[3];
        float C = sc[0] + sc[1] + sc[2] + sc[3];
        if (C < 1.0f) C = 1.0f;
        out[0] = K / C;
    }
}

extern "C" void kernel_launch(void* const* d_in, const int* in_sizes, int n_in,
                              void* d_out, int out_size, void* d_ws, size_t ws_size,
                              hipStream_t stream) {
    const float* scores = (const float*)d_in[0];
    const int* rankings = (const int*)d_in[1];
    const unsigned char* mask = (const unsigned char*)d_in[2];
    float* out = (float*)d_out;

    const int total = in_sizes[0];                 // B*H = 16777216
    const int nrows = total / H;                   // 524288 rows
    const int blocks = 2048;                       // 8192 waves, all resident
    const long long tgroups = ((long long)nrows + 3) >> 2;      // 131072
    const long long waves = (long long)blocks * WPB;            // 8192
    int ipw = (int)((tgroups + waves - 1) / waves);             // 16
    if (ipw < 1) ipw = 1;

    float* part_kl  = (float*)d_ws;               // [0, blocks)
    float* part_cnt = (float*)d_ws + blocks;      // [blocks, 2*blocks)

    listwise_kernel<<<blocks, BLK, 0, stream>>>(
        scores, rankings, mask, part_kl, part_cnt, nrows, ipw);

    finalize_kernel<<<1, 256, 0, stream>>>(part_kl, part_cnt, out, blocks);
}